// Round 7
// baseline (183.103 us; speedup 1.0000x reference)
//
#include <hip/hip_runtime.h>
#include <hip/hip_bf16.h>
#include <math.h>

typedef __bf16 bf16x8 __attribute__((ext_vector_type(8)));
typedef float  f32x4  __attribute__((ext_vector_type(4)));

#define M_DIM 16384
#define N_DIM 512
#define K_DIM 512
#define TBL_N 1024     // I_in(V) lerp table over [-4,4]

__device__ inline bf16x8 pack_bf16x8(float4 lo, float4 hi) {
    bf16x8 r;
    r[0] = (__bf16)lo.x; r[1] = (__bf16)lo.y; r[2] = (__bf16)lo.z; r[3] = (__bf16)lo.w;
    r[4] = (__bf16)hi.x; r[5] = (__bf16)hi.y; r[6] = (__bf16)hi.z; r[7] = (__bf16)hi.w;
    return r;
}

// Block tile 256m x 64n, 4 waves stacked in m; wave tile 64m x 64n (mt=4, nt=4).
// NO LDS GEMM tiles, NO K-loop barriers. Direct global->frag loads with an
// explicit rotate-buffer software pipeline: pack step s from regs loaded at
// step s-1, immediately re-issue step s+1's load into the same regs.
// sched_barrier(0) pins loads before the MFMA block so the compiler cannot
// collapse the pipeline (R5/R6 failure mode) -> waitcnts become vmcnt(N>0).
__global__ __launch_bounds__(256, 2)
void snn_fused_kernel(const float* __restrict__ x, const float* __restrict__ W,
                      const float* __restrict__ gNa_p, const float* __restrict__ gK_p,
                      const float* __restrict__ gL_p, float* __restrict__ out)
{
    __shared__ float tbl[TBL_N + 1];

    const int tid = threadIdx.x;

    // ---- exact-HH I_in(V) table (the only transcendentals in the kernel) ----
    {
        const float gNa = *gNa_p, gK = *gK_p, gL = *gL_p;
        for (int i = tid; i <= TBL_N; i += 256) {
            const float V = -4.0f + (8.0f / TBL_N) * i;
            const float am = 0.1f * (V + 40.0f) / (1.0f - expf(-(V + 40.0f) * 0.1f));
            const float bm = 4.0f * expf(-(V + 65.0f) * (1.0f / 18.0f));
            const float ah = 0.07f * expf(-(V + 65.0f) * 0.05f);
            const float bh = 1.0f / (1.0f + expf(-(V + 35.0f) * 0.1f));
            const float an = 0.01f * (V + 55.0f) / (1.0f - expf(-(V + 55.0f) * 0.1f));
            const float bn = 0.125f * expf(-(V + 65.0f) * 0.0125f);
            const float m = 0.05f + 0.1f * (am * 0.95f - bm * 0.05f);
            const float h = 0.60f + 0.1f * (ah * 0.40f - bh * 0.60f);
            const float n = 0.32f + 0.1f * (an * 0.68f - bn * 0.32f);
            const float I_ion = gNa * m * m * m * h * (V - 50.0f)
                              + gK * (n * n) * (n * n) * (V + 77.0f)
                              + gL * (V + 54.4f);
            tbl[i] = I_ion + V;
        }
    }
    __syncthreads();   // the ONLY barrier in the kernel

    // ---- XCD swizzle: xcd owns an 8-tile bm band (8*256 rows * 2KB = 4 MB
    // of x = its L2); consecutive slots sweep all 8 bn for one bm.
    const int id   = blockIdx.x;        // 0..511
    const int xcd  = id & 7;
    const int slot = id >> 3;           // 0..63
    const int bm   = xcd * 8 + (slot >> 3);   // 0..63
    const int bn   = slot & 7;                // 0..7

    const int wave = tid >> 6;
    const int lane = tid & 63;
    const int lr   = lane & 15;
    const int quad = lane >> 4;

    const long gmBase = (long)bm * 256 + wave * 64;  // wave's first A row
    const int  gnBase = bn * 64;                     // block-shared B rows

    // 8 per-lane base pointers; all 16 K-steps use immediate offsets
    // (s*128 B + {0,64} B, max 1936+16 floats*4 < 4 KB imm range).
    const float* aB0 = x + (gmBase +  0 + lr) * (long)K_DIM + quad * 8;
    const float* aB1 = x + (gmBase + 16 + lr) * (long)K_DIM + quad * 8;
    const float* aB2 = x + (gmBase + 32 + lr) * (long)K_DIM + quad * 8;
    const float* aB3 = x + (gmBase + 48 + lr) * (long)K_DIM + quad * 8;
    const float* bB0 = W + (gnBase +  0 + lr) * (long)K_DIM + quad * 8;
    const float* bB1 = W + (gnBase + 16 + lr) * (long)K_DIM + quad * 8;
    const float* bB2 = W + (gnBase + 32 + lr) * (long)K_DIM + quad * 8;
    const float* bB3 = W + (gnBase + 48 + lr) * (long)K_DIM + quad * 8;

    f32x4 acc[4][4] = {};

    // prime the pipeline: step-0 operands
    float4 pf[16];
    pf[0]  = *(const float4*)(aB0);     pf[1]  = *(const float4*)(aB0 + 4);
    pf[2]  = *(const float4*)(aB1);     pf[3]  = *(const float4*)(aB1 + 4);
    pf[4]  = *(const float4*)(aB2);     pf[5]  = *(const float4*)(aB2 + 4);
    pf[6]  = *(const float4*)(aB3);     pf[7]  = *(const float4*)(aB3 + 4);
    pf[8]  = *(const float4*)(bB0);     pf[9]  = *(const float4*)(bB0 + 4);
    pf[10] = *(const float4*)(bB1);     pf[11] = *(const float4*)(bB1 + 4);
    pf[12] = *(const float4*)(bB2);     pf[13] = *(const float4*)(bB2 + 4);
    pf[14] = *(const float4*)(bB3);     pf[15] = *(const float4*)(bB3 + 4);

    #pragma unroll
    for (int s = 0; s < 16; ++s) {
        // next step's float offset (last iter redundantly reloads s=15: L1-hot)
        const int noff = (s + 1 < 16 ? s + 1 : s) * 32;
        bf16x8 af[4], bfr[4];

        af[0] = pack_bf16x8(pf[0], pf[1]);
        pf[0]  = *(const float4*)(aB0 + noff);  pf[1]  = *(const float4*)(aB0 + noff + 4);
        af[1] = pack_bf16x8(pf[2], pf[3]);
        pf[2]  = *(const float4*)(aB1 + noff);  pf[3]  = *(const float4*)(aB1 + noff + 4);
        af[2] = pack_bf16x8(pf[4], pf[5]);
        pf[4]  = *(const float4*)(aB2 + noff);  pf[5]  = *(const float4*)(aB2 + noff + 4);
        af[3] = pack_bf16x8(pf[6], pf[7]);
        pf[6]  = *(const float4*)(aB3 + noff);  pf[7]  = *(const float4*)(aB3 + noff + 4);
        bfr[0] = pack_bf16x8(pf[8], pf[9]);
        pf[8]  = *(const float4*)(bB0 + noff);  pf[9]  = *(const float4*)(bB0 + noff + 4);
        bfr[1] = pack_bf16x8(pf[10], pf[11]);
        pf[10] = *(const float4*)(bB1 + noff);  pf[11] = *(const float4*)(bB1 + noff + 4);
        bfr[2] = pack_bf16x8(pf[12], pf[13]);
        pf[12] = *(const float4*)(bB2 + noff);  pf[13] = *(const float4*)(bB2 + noff + 4);
        bfr[3] = pack_bf16x8(pf[14], pf[15]);
        pf[14] = *(const float4*)(bB3 + noff);  pf[15] = *(const float4*)(bB3 + noff + 4);

        // pin: loads/packs above may not sink below; MFMAs may not hoist above
        __builtin_amdgcn_sched_barrier(0);

        #pragma unroll
        for (int mt = 0; mt < 4; ++mt)
            #pragma unroll
            for (int nt = 0; nt < 4; ++nt)
                acc[mt][nt] = __builtin_amdgcn_mfma_f32_16x16x32_bf16(
                    af[mt], bfr[nt], acc[mt][nt], 0, 0, 0);
    }

    // ---- table-lerp epilogue, all 3 planes stored in-kernel ----
    float* outS = out;
    float* outV = out + (long)M_DIM * N_DIM;
    float* outW = out + 2L * M_DIM * N_DIM;

    #pragma unroll
    for (int mt = 0; mt < 4; ++mt) {
        #pragma unroll
        for (int i = 0; i < 4; ++i) {
            const long gm = gmBase + mt * 16 + quad * 4 + i;
            #pragma unroll
            for (int nt = 0; nt < 4; ++nt) {
                const int gn = gnBase + nt * 16 + lr;
                const float V = acc[mt][nt][i];

                float u = (V + 4.0f) * (TBL_N / 8.0f);
                u = fminf(fmaxf(u, 0.0f), (float)TBL_N - 0.001f);
                const int   iu = (int)u;
                const float f  = u - (float)iu;
                const float t0 = tbl[iu];
                const float t1 = tbl[iu + 1];
                const float I_in = t0 + f * (t1 - t0);

                const float v_new = -65.0f + I_in * 0.005f;
                const float spike = (v_new >= -50.0f) ? 1.0f : 0.0f;
                const float w_new = (0.5f * (v_new + 65.0f) + 0.1f * spike) * 0.001f;
                const float v_rs  = (spike > 0.5f) ? -65.0f : v_new;

                const long idx = gm * N_DIM + gn;
                outS[idx] = spike;
                outV[idx] = v_rs;
                outW[idx] = w_new;
            }
        }
    }
}

extern "C" void kernel_launch(void* const* d_in, const int* in_sizes, int n_in,
                              void* d_out, int out_size, void* d_ws, size_t ws_size,
                              hipStream_t stream) {
    const float* x   = (const float*)d_in[0];
    const float* W   = (const float*)d_in[1];
    const float* gNa = (const float*)d_in[2];
    const float* gK  = (const float*)d_in[3];
    const float* gL  = (const float*)d_in[4];
    float* out = (float*)d_out;

    dim3 grid((M_DIM / 256) * (N_DIM / 64));   // 64*8 = 512 blocks = 2/CU
    dim3 block(256);
    hipLaunchKernelGGL(snn_fused_kernel, grid, block, 0, stream, x, W, gNa, gK, gL, out);
}

// Round 8
// 149.016 us; speedup vs baseline: 1.2288x; 1.2288x over previous
//
#include <hip/hip_runtime.h>
#include <hip/hip_bf16.h>
#include <math.h>

typedef __bf16 bf16x4 __attribute__((ext_vector_type(4)));
typedef __bf16 bf16x8 __attribute__((ext_vector_type(8)));
typedef float  f32x4  __attribute__((ext_vector_type(4)));

#define M_DIM 16384
#define N_DIM 512
#define K_DIM 512
#define TBL_N 1024

#define X_ELEMS ((long)M_DIM * K_DIM)          // 8388608
#define W_ELEMS ((long)N_DIM * K_DIM)          // 262144
#define WS_NEED ((X_ELEMS + W_ELEMS) * 2)      // 17.3 MB bf16

// ---------------- kernel 1: fp32 -> bf16 pre-convert into d_ws ----------------
__global__ __launch_bounds__(256)
void convert_kernel(const float* __restrict__ x, const float* __restrict__ W,
                    __bf16* __restrict__ xb, __bf16* __restrict__ wb)
{
    const long XN8 = X_ELEMS / 8;
    const long T8  = XN8 + W_ELEMS / 8;
    for (long i = (long)blockIdx.x * 256 + threadIdx.x; i < T8;
         i += (long)gridDim.x * 256) {
        const float* src;
        __bf16* dst;
        if (i < XN8) { src = x + i * 8;          dst = xb + i * 8; }
        else         { src = W + (i - XN8) * 8;  dst = wb + (i - XN8) * 8; }
        float4 a = *(const float4*)src;
        float4 b = *(const float4*)(src + 4);
        bf16x8 r;
        r[0] = (__bf16)a.x; r[1] = (__bf16)a.y; r[2] = (__bf16)a.z; r[3] = (__bf16)a.w;
        r[4] = (__bf16)b.x; r[5] = (__bf16)b.y; r[6] = (__bf16)b.z; r[7] = (__bf16)b.w;
        *(bf16x8*)dst = r;
    }
}

// async global->LDS DMA, 16 B per lane, wave-uniform LDS base + lane*16
__device__ inline void gl_lds16(const __bf16* g, __bf16* l) {
    __builtin_amdgcn_global_load_lds(
        (const __attribute__((address_space(1))) void*)g,
        (__attribute__((address_space(3))) void*)l, 16, 0, 0);
}

// ---------------- kernel 2: m97-style GEMM + fused HH epilogue ----------------
// 128x128 tile, BK=64, 4 waves each 64x64 (4x4 frags). Staging = 8
// global_load_lds_dwordx4 per thread per K-tile (no VALU, no VGPR roundtrip).
// XOR chunk-swizzle on the GLOBAL source address (LDS dest order is fixed by
// the DMA) -> frag ds_read_b128 is 2-way max (free) instead of 16-way.
__global__ __launch_bounds__(256, 2)
void gemm_hh_kernel(const __bf16* __restrict__ xb, const __bf16* __restrict__ wb,
                    const float* __restrict__ gNa_p, const float* __restrict__ gK_p,
                    const float* __restrict__ gL_p, float* __restrict__ out)
{
    __shared__ __bf16 sA[128 * 64];
    __shared__ __bf16 sB[128 * 64];
    __shared__ float  tbl[TBL_N + 1];

    const int tid = threadIdx.x;

    // ---- exact-HH I_in(V) table ----
    {
        const float gNa = *gNa_p, gK = *gK_p, gL = *gL_p;
        for (int i = tid; i <= TBL_N; i += 256) {
            const float V = -4.0f + (8.0f / TBL_N) * i;
            const float am = 0.1f * (V + 40.0f) / (1.0f - expf(-(V + 40.0f) * 0.1f));
            const float bm_ = 4.0f * expf(-(V + 65.0f) * (1.0f / 18.0f));
            const float ah = 0.07f * expf(-(V + 65.0f) * 0.05f);
            const float bh = 1.0f / (1.0f + expf(-(V + 35.0f) * 0.1f));
            const float an = 0.01f * (V + 55.0f) / (1.0f - expf(-(V + 55.0f) * 0.1f));
            const float bn_ = 0.125f * expf(-(V + 65.0f) * 0.0125f);
            const float m = 0.05f + 0.1f * (am * 0.95f - bm_ * 0.05f);
            const float h = 0.60f + 0.1f * (ah * 0.40f - bh * 0.60f);
            const float n = 0.32f + 0.1f * (an * 0.68f - bn_ * 0.32f);
            const float I_ion = gNa * m * m * m * h * (V - 50.0f)
                              + gK * (n * n) * (n * n) * (V + 77.0f)
                              + gL * (V + 54.4f);
            tbl[i] = I_ion + V;
        }
    }

    // XCD swizzle: each XCD owns 16 bm tiles (16*128 rows * 1 KB = 2 MB bf16 x = L2)
    const int id   = blockIdx.x;            // 0..511
    const int xcd  = id & 7;
    const int slot = id >> 3;               // 0..63
    const int bm   = xcd * 16 + (slot >> 2);    // 0..127
    const int bn   = slot & 3;                  // 0..3

    const int wv = tid >> 6;
    const int ln = tid & 63;
    const int lr = ln & 15;
    const int quad = ln >> 4;
    const int wM = (wv & 1) * 64;
    const int wN = (wv >> 1) * 64;

    // DMA source pattern: lane ln covers row rw=ln>>3 (of an 8-row group),
    // chunk slot ch=ln&7; global chunk fetched = ch ^ rw (XOR swizzle).
    const int rw  = ln >> 3;
    const int ch  = ln & 7;
    const int chx = (ch ^ rw) * 8;          // bf16 elems within the 64-wide row
    const __bf16* aSrc = xb + ((long)bm * 128 + 32 * wv + rw) * K_DIM + chx;
    const __bf16* bSrc = wb + ((long)bn * 128 + 32 * wv + rw) * K_DIM + chx;

    f32x4 acc[4][4] = {};

    for (int kt = 0; kt < K_DIM; kt += 64) {
        // 8 DMA issues per thread: A rows 32wv..+31, B rows 32wv..+31
        #pragma unroll
        for (int j = 0; j < 4; ++j) {
            gl_lds16(aSrc + (long)(8 * j) * K_DIM + kt, sA + (32 * wv + 8 * j) * 64);
            gl_lds16(bSrc + (long)(8 * j) * K_DIM + kt, sB + (32 * wv + 8 * j) * 64);
        }
        __syncthreads();   // drains vmcnt -> DMA complete

        #pragma unroll
        for (int kk = 0; kk < 2; ++kk) {
            bf16x8 af[4], bfr[4];
            #pragma unroll
            for (int t = 0; t < 4; ++t) {
                const int ra = wM + t * 16 + lr;
                const int rb = wN + t * 16 + lr;
                const int cidx = quad + 4 * kk;
                af[t]  = *(const bf16x8*)(sA + ra * 64 + ((cidx ^ (lr & 7)) * 8));
                bfr[t] = *(const bf16x8*)(sB + rb * 64 + ((cidx ^ (lr & 7)) * 8));
            }
            #pragma unroll
            for (int mt = 0; mt < 4; ++mt)
                #pragma unroll
                for (int nt = 0; nt < 4; ++nt)
                    acc[mt][nt] = __builtin_amdgcn_mfma_f32_16x16x32_bf16(
                        af[mt], bfr[nt], acc[mt][nt], 0, 0, 0);
        }
        __syncthreads();   // protect LDS before next DMA overwrite
    }

    // ---- table-lerp epilogue, 3 planes ----
    float* outS = out;
    float* outV = out + (long)M_DIM * N_DIM;
    float* outW = out + 2L * M_DIM * N_DIM;

    #pragma unroll
    for (int mt = 0; mt < 4; ++mt) {
        #pragma unroll
        for (int i = 0; i < 4; ++i) {
            const long gm = (long)bm * 128 + wM + mt * 16 + quad * 4 + i;
            #pragma unroll
            for (int nt = 0; nt < 4; ++nt) {
                const int gn = bn * 128 + wN + nt * 16 + lr;
                const float V = acc[mt][nt][i];

                float u = (V + 4.0f) * (TBL_N / 8.0f);
                u = fminf(fmaxf(u, 0.0f), (float)TBL_N - 0.001f);
                const int   iu = (int)u;
                const float f  = u - (float)iu;
                const float t0 = tbl[iu];
                const float t1 = tbl[iu + 1];
                const float I_in = t0 + f * (t1 - t0);

                const float v_new = -65.0f + I_in * 0.005f;
                const float spike = (v_new >= -50.0f) ? 1.0f : 0.0f;
                const float w_new = (0.5f * (v_new + 65.0f) + 0.1f * spike) * 0.001f;
                const float v_rs  = (spike > 0.5f) ? -65.0f : v_new;

                const long idx = gm * N_DIM + gn;
                outS[idx] = spike;
                outV[idx] = v_rs;
                outW[idx] = w_new;
            }
        }
    }
}

// ---------------- fallback (R6 structure) if d_ws is too small ----------------
#define BMf 64
#define BNf 128
#define LDSTf 72
__global__ __launch_bounds__(256, 4)
void snn_fallback_kernel(const float* __restrict__ x, const float* __restrict__ W,
                         const float* __restrict__ gNa_p, const float* __restrict__ gK_p,
                         const float* __restrict__ gL_p, float* __restrict__ out)
{
    __shared__ __bf16 sA[BMf * LDSTf];
    __shared__ __bf16 sB[BNf * LDSTf];
    __shared__ float  tbl[TBL_N + 1];

    const int tid = threadIdx.x;
    const int id   = blockIdx.x;
    const int xcd  = id & 7;
    const int slot = id >> 3;
    const int bm   = xcd * 32 + (slot >> 2);
    const int bn   = slot & 3;

    const int c4 = (tid & 15) * 4;
    const int r0 = tid >> 4;
    const float* xBase = x + (long)(bm * BMf + r0) * K_DIM + c4;
    const float* wBase = W + (long)(bn * BNf + r0) * K_DIM + c4;

    const int wave = tid >> 6;
    const int lane = tid & 63;
    const int wM   = (wave & 1) * 32;
    const int wN   = (wave >> 1) * 64;
    const int lr   = lane & 15;
    const int quad = lane >> 4;

    f32x4 acc[2][4] = {};
    float4 pa[4], pb[8];
    #pragma unroll
    for (int rr = 0; rr < 4; ++rr) pa[rr] = *(const float4*)(xBase + (long)rr * 16 * K_DIM);
    #pragma unroll
    for (int rr = 0; rr < 8; ++rr) pb[rr] = *(const float4*)(wBase + (long)rr * 16 * K_DIM);

    {
        const float gNa = *gNa_p, gK = *gK_p, gL = *gL_p;
        for (int i = tid; i <= TBL_N; i += 256) {
            const float V = -4.0f + (8.0f / TBL_N) * i;
            const float am = 0.1f * (V + 40.0f) / (1.0f - expf(-(V + 40.0f) * 0.1f));
            const float bm_ = 4.0f * expf(-(V + 65.0f) * (1.0f / 18.0f));
            const float ah = 0.07f * expf(-(V + 65.0f) * 0.05f);
            const float bh = 1.0f / (1.0f + expf(-(V + 35.0f) * 0.1f));
            const float an = 0.01f * (V + 55.0f) / (1.0f - expf(-(V + 55.0f) * 0.1f));
            const float bn_ = 0.125f * expf(-(V + 65.0f) * 0.0125f);
            const float m = 0.05f + 0.1f * (am * 0.95f - bm_ * 0.05f);
            const float h = 0.60f + 0.1f * (ah * 0.40f - bh * 0.60f);
            const float n = 0.32f + 0.1f * (an * 0.68f - bn_ * 0.32f);
            tbl[i] = gNa * m * m * m * h * (V - 50.0f)
                   + gK * (n * n) * (n * n) * (V + 77.0f)
                   + gL * (V + 54.4f) + V;
        }
    }

    for (int kt = 0; kt < K_DIM; kt += 64) {
        const int ktn = (kt + 64 < K_DIM) ? kt + 64 : kt;
        const float* xp = xBase + ktn;
        const float* wp = wBase + ktn;
        #pragma unroll
        for (int rr = 0; rr < 4; ++rr) {
            float4 v = pa[rr];
            pa[rr] = *(const float4*)(xp + (long)rr * 16 * K_DIM);
            bf16x4 b = { (__bf16)v.x, (__bf16)v.y, (__bf16)v.z, (__bf16)v.w };
            *(bf16x4*)(&sA[(r0 + rr * 16) * LDSTf + c4]) = b;
        }
        #pragma unroll
        for (int rr = 0; rr < 8; ++rr) {
            float4 v = pb[rr];
            pb[rr] = *(const float4*)(wp + (long)rr * 16 * K_DIM);
            bf16x4 b = { (__bf16)v.x, (__bf16)v.y, (__bf16)v.z, (__bf16)v.w };
            *(bf16x4*)(&sB[(r0 + rr * 16) * LDSTf + c4]) = b;
        }
        __syncthreads();
        #pragma unroll
        for (int ks = 0; ks < 64; ks += 32) {
            bf16x8 af[2], bfr[4];
            #pragma unroll
            for (int t = 0; t < 2; ++t)
                af[t]  = *(const bf16x8*)(&sA[(wM + t * 16 + lr) * LDSTf + ks + quad * 8]);
            #pragma unroll
            for (int t = 0; t < 4; ++t)
                bfr[t] = *(const bf16x8*)(&sB[(wN + t * 16 + lr) * LDSTf + ks + quad * 8]);
            #pragma unroll
            for (int mt = 0; mt < 2; ++mt)
                #pragma unroll
                for (int nt = 0; nt < 4; ++nt)
                    acc[mt][nt] = __builtin_amdgcn_mfma_f32_16x16x32_bf16(
                        af[mt], bfr[nt], acc[mt][nt], 0, 0, 0);
        }
        __syncthreads();
    }

    float* outS = out;
    float* outV = out + (long)M_DIM * N_DIM;
    float* outW = out + 2L * M_DIM * N_DIM;
    #pragma unroll
    for (int mt = 0; mt < 2; ++mt) {
        #pragma unroll
        for (int i = 0; i < 4; ++i) {
            const long gm = (long)bm * BMf + wM + mt * 16 + quad * 4 + i;
            #pragma unroll
            for (int nt = 0; nt < 4; ++nt) {
                const int gn = bn * BNf + wN + nt * 16 + lr;
                const float V = acc[mt][nt][i];
                float u = (V + 4.0f) * (TBL_N / 8.0f);
                u = fminf(fmaxf(u, 0.0f), (float)TBL_N - 0.001f);
                const int   iu = (int)u;
                const float f  = u - (float)iu;
                const float I_in = tbl[iu] + f * (tbl[iu + 1] - tbl[iu]);
                const float v_new = -65.0f + I_in * 0.005f;
                const float spike = (v_new >= -50.0f) ? 1.0f : 0.0f;
                const float w_new = (0.5f * (v_new + 65.0f) + 0.1f * spike) * 0.001f;
                const float v_rs  = (spike > 0.5f) ? -65.0f : v_new;
                const long idx = gm * N_DIM + gn;
                outS[idx] = spike; outV[idx] = v_rs; outW[idx] = w_new;
            }
        }
    }
}

extern "C" void kernel_launch(void* const* d_in, const int* in_sizes, int n_in,
                              void* d_out, int out_size, void* d_ws, size_t ws_size,
                              hipStream_t stream) {
    const float* x   = (const float*)d_in[0];
    const float* W   = (const float*)d_in[1];
    const float* gNa = (const float*)d_in[2];
    const float* gK  = (const float*)d_in[3];
    const float* gL  = (const float*)d_in[4];
    float* out = (float*)d_out;

    if (ws_size >= (size_t)WS_NEED) {
        __bf16* xb = (__bf16*)d_ws;
        __bf16* wb = xb + X_ELEMS;
        hipLaunchKernelGGL(convert_kernel, dim3(1024), dim3(256), 0, stream, x, W, xb, wb);
        hipLaunchKernelGGL(gemm_hh_kernel, dim3(512), dim3(256), 0, stream,
                           xb, wb, gNa, gK, gL, out);
    } else {
        hipLaunchKernelGGL(snn_fallback_kernel, dim3(1024), dim3(256), 0, stream,
                           x, W, gNa, gK, gL, out);
    }
}